// Round 8
// baseline (421.096 us; speedup 1.0000x reference)
//
#include <hip/hip_runtime.h>
#include <math.h>

// GATv2 2-layer: N=50000, E=800000, HEADS=8, C=32, ODIM=256, IN_C=64
#define HEADS 8
#define CDIM 32
#define ODIM 256

typedef _Float16 h2 __attribute__((ext_vector_type(2)));
typedef _Float16 h8v __attribute__((ext_vector_type(8)));
union H8 { h8v v; h2 p[4]; };

#if __has_builtin(__builtin_amdgcn_fdot2)
#define FDOT2(a,b,c) __builtin_amdgcn_fdot2((a),(b),(c),false)
#else
static __device__ __forceinline__ float fdot2_sw(h2 a, h2 b, float c){
  return fmaf((float)a.x, (float)b.x, fmaf((float)a.y, (float)b.y, c));
}
#define FDOT2(a,b,c) fdot2_sw((a),(b),(c))
#endif

__device__ __forceinline__ float lrelu(float v, float s){ return fmaxf(v, s*v); }

// ---------------- CSR build ----------------
__global__ void count_kernel(const int* __restrict__ src, const int* __restrict__ dst,
                             int* __restrict__ counts, int e){
  int i = blockIdx.x*256 + threadIdx.x;
  if (i < e){
    int s = src[i], d = dst[i];
    if (s != d) atomicAdd(counts + d, 1);   // src==dst originals are masked (PyG removes them)
  }
}

// ---- 3-phase parallel scan ----
__global__ void block_sum_kernel(const int* __restrict__ counts, int* __restrict__ bsums, int n){
  int i = blockIdx.x*256 + threadIdx.x;
  int v = (i < n) ? counts[i] : 0;
#pragma unroll
  for (int off=1; off<64; off<<=1) v += __shfl_xor(v, off);
  __shared__ int ws[4];
  int lane = threadIdx.x & 63, w = threadIdx.x >> 6;
  if (lane == 0) ws[w] = v;
  __syncthreads();
  if (threadIdx.x == 0) bsums[blockIdx.x] = ws[0]+ws[1]+ws[2]+ws[3];
}

__global__ __launch_bounds__(1024) void scan_bsums_kernel(int* __restrict__ bsums, int nb){
  __shared__ int s[1024];
  int t = threadIdx.x;
  int v = (t < nb) ? bsums[t] : 0;
  s[t] = v;
  __syncthreads();
  for (int off=1; off<1024; off<<=1){
    int u = (t >= off) ? s[t-off] : 0;
    __syncthreads();
    s[t] += u;
    __syncthreads();
  }
  if (t < nb) bsums[t] = s[t] - v;   // exclusive
}

__global__ void local_scan_kernel(const int* __restrict__ counts, const int* __restrict__ bsums,
                                  int* __restrict__ indptr, int* __restrict__ cursor, int n){
  __shared__ int s[256];
  int t = threadIdx.x;
  int i = blockIdx.x*256 + t;
  int v = (i < n) ? counts[i] : 0;
  s[t] = v;
  __syncthreads();
  for (int off=1; off<256; off<<=1){
    int u = (t >= off) ? s[t-off] : 0;
    __syncthreads();
    s[t] += u;
    __syncthreads();
  }
  int excl = s[t] - v + bsums[blockIdx.x];
  if (i < n){ indptr[i] = excl; cursor[i] = excl; }
  if (i == n-1) indptr[n] = excl + v;
}

__global__ void scatter_kernel(const int* __restrict__ src, const int* __restrict__ dst,
                               int* __restrict__ cursor, int* __restrict__ csr_src, int e){
  int i = blockIdx.x*256 + threadIdx.x;
  if (i < e){
    int s = src[i], d = dst[i];
    if (s != d){
      int p = atomicAdd(cursor + d, 1);
      csr_src[p] = s;
    }
  }
}

// ---------------- dense GEMM: out[n,o] = sum_k X[n,k]*W[o,k] + b[o] ----------------
// LDS-tiled, l+r fused (shares the x tile). Block = 64 nodes x 64 outputs,
// thread micro-tile = 4 nodes x 4 outputs x {l,r}. outl fp16 (gather operand),
// outr fp32 (converted in edge kernel). R4-R6 proven.
template<int K>
__global__ __launch_bounds__(256, 3) void gemm_kernel(const float* __restrict__ X,
    const float* __restrict__ Wl, const float* __restrict__ bl,
    const float* __restrict__ Wr, const float* __restrict__ br,
    _Float16* __restrict__ outl, float* __restrict__ outr, int n){
  const int KP = K + 4;
  __shared__ float xt[64*(K+4)];
  __shared__ float wt[2][64*(K+4)];
  int t = threadIdx.x;
  int n0 = blockIdx.x*64;
  int o0 = blockIdx.y*64;

  for (int idx = t; idx < 64*(K/4); idx += 256){
    int row = idx/(K/4), c = (idx%(K/4))*4;
    int node = n0 + row; if (node >= n) node = n-1;   // clamp; stores guarded
    float4 v = *(const float4*)(X + (size_t)node*K + c);
    *(float4*)(xt + row*KP + c) = v;
  }
  for (int idx = t; idx < 64*(K/4); idx += 256){
    int row = idx/(K/4), c = (idx%(K/4))*4;
    float4 vl = *(const float4*)(Wl + (size_t)(o0+row)*K + c);
    float4 vr = *(const float4*)(Wr + (size_t)(o0+row)*K + c);
    *(float4*)(wt[0] + row*KP + c) = vl;
    *(float4*)(wt[1] + row*KP + c) = vr;
  }
  __syncthreads();

  int og = t & 15;          // outputs o0 + og + 16j
  int ng = t >> 4;          // nodes   n0 + ng + 16i
  float accl[4][4] = {{0.f}}, accr[4][4] = {{0.f}};

#pragma unroll 2
  for (int kk = 0; kk < K; kk += 4){
    float4 xv[4], wl4[4], wr4[4];
#pragma unroll
    for (int i=0;i<4;i++) xv[i] = *(const float4*)(xt + (ng+16*i)*KP + kk);
#pragma unroll
    for (int j=0;j<4;j++){
      wl4[j] = *(const float4*)(wt[0] + (og+16*j)*KP + kk);
      wr4[j] = *(const float4*)(wt[1] + (og+16*j)*KP + kk);
    }
#pragma unroll
    for (int i=0;i<4;i++){
#pragma unroll
      for (int j=0;j<4;j++){
        accl[i][j] = fmaf(xv[i].x, wl4[j].x, fmaf(xv[i].y, wl4[j].y,
                     fmaf(xv[i].z, wl4[j].z, fmaf(xv[i].w, wl4[j].w, accl[i][j]))));
        accr[i][j] = fmaf(xv[i].x, wr4[j].x, fmaf(xv[i].y, wr4[j].y,
                     fmaf(xv[i].z, wr4[j].z, fmaf(xv[i].w, wr4[j].w, accr[i][j]))));
      }
    }
  }

  float bvl[4], bvr[4];
#pragma unroll
  for (int j=0;j<4;j++){ bvl[j] = bl[o0+og+16*j]; bvr[j] = br[o0+og+16*j]; }
#pragma unroll
  for (int i=0;i<4;i++){
    int node = n0 + ng + 16*i;
    if (node < n){
      _Float16* pl = outl + (size_t)node*ODIM + o0 + og;
      float*    pr = outr + (size_t)node*ODIM + o0 + og;
#pragma unroll
      for (int j=0;j<4;j++){
        pl[16*j] = (_Float16)(accl[i][j] + bvl[j]);
        pr[16*j] = accr[i][j] + bvr[j];
      }
    }
  }
}

// ---------------- fused edge softmax + aggregate ----------------
// One wave per node, TWO edges per iteration.
// Lane l: edge-slot = l>>5, s = l&31, head = s>>2, chgroup = s&3 (8 channels).
// Element offset in a row = s*8 -> lane loads h8 (16B); 32 lanes cover one
// 512B row, the full wave gathers TWO rows per load instruction.
// HARDENED: no clamped speculative loads — every gather is guarded with an
// explicit zero fallback; all masks identical to the validated math.
// exp2 without max-subtraction (scores small; fp32 exp2 overflow-safe),
// att pre-scaled by log2e. Aggregation fp32.
__global__ __launch_bounds__(256) void edge_kernel(
    const _Float16* __restrict__ xl, const float* __restrict__ xr,
    const float* __restrict__ att, const float* __restrict__ bias,
    const int* __restrict__ indptr, const int* __restrict__ csr_src,
    float* __restrict__ out, int n, int act)
{
  int wid = blockIdx.x*4 + (threadIdx.x >> 6);
  if (wid >= n) return;
  int lane = threadIdx.x & 63;
  int s = lane & 31;
  int slot = lane >> 5;
  const float LOG2E = 1.44269504088896341f;

  float4 a0 = *(const float4*)(att + s*8);
  float4 a1 = *(const float4*)(att + s*8 + 4);
  h2 at[4];
  at[0] = (h2){(_Float16)(a0.x*LOG2E), (_Float16)(a0.y*LOG2E)};
  at[1] = (h2){(_Float16)(a0.z*LOG2E), (_Float16)(a0.w*LOG2E)};
  at[2] = (h2){(_Float16)(a1.x*LOG2E), (_Float16)(a1.y*LOG2E)};
  at[3] = (h2){(_Float16)(a1.z*LOG2E), (_Float16)(a1.w*LOG2E)};
  const h2 c02 = {(_Float16)0.2f, (_Float16)0.2f};

  float4 xra = *(const float4*)(xr + (size_t)wid*ODIM + s*8);
  float4 xrb = *(const float4*)(xr + (size_t)wid*ODIM + s*8 + 4);
  H8 xr8;
  xr8.p[0] = (h2){(_Float16)xra.x, (_Float16)xra.y};
  xr8.p[1] = (h2){(_Float16)xra.z, (_Float16)xra.w};
  xr8.p[2] = (h2){(_Float16)xrb.x, (_Float16)xrb.y};
  xr8.p[3] = (h2){(_Float16)xrb.z, (_Float16)xrb.w};

  H8 self; self.v = *(const h8v*)(xl + (size_t)wid*ODIM + s*8);

  auto score8 = [&](const H8& c)->float{
    float d = 0.f;
#pragma unroll
    for (int j=0;j<4;j++){
      h2 t = c.p[j] + xr8.p[j];
      h2 q = __builtin_elementwise_max(t, t * c02);
      d = FDOT2(q, at[j], d);
    }
    d += __shfl_xor(d, 1);   // reduce over chgroup quad
    d += __shfl_xor(d, 2);
    return d;
  };

  // self-loop seed (counted once: slot1 masked)
  float pse = exp2f(score8(self));
  if (slot) pse = 0.f;
  float denom = pse;
  float acc[8];
#pragma unroll
  for (int j=0;j<8;j++) acc[j] = pse * (float)self.v[j];

  int beg = __builtin_amdgcn_readfirstlane(indptr[wid]);
  int end = __builtin_amdgcn_readfirstlane(indptr[wid+1]);
  int cnt = end - beg;
  int base = beg + slot;   // this lane's edge stream: base, base+2, base+4, ...

  H8 r0, r1;
  r0.v = (h8v)(_Float16)0;
  r1.v = (h8v)(_Float16)0;
  if (base < end){
    int sI = csr_src[base];
    r0.v = *(const h8v*)(xl + (size_t)sI*ODIM + s*8);
  }
  if (base + 2 < end){
    int sI = csr_src[base+2];
    r1.v = *(const h8v*)(xl + (size_t)sI*ODIM + s*8);
  }

  for (int k = 0; k < cnt; k += 2){
    H8 cur = r0;
    bool valid = (base + k) < end;
    r0 = r1;
    r1.v = (h8v)(_Float16)0;
    if (base + k + 4 < end){
      int sI = csr_src[base+k+4];
      r1.v = *(const h8v*)(xl + (size_t)sI*ODIM + s*8);   // prefetch pair+2
    }
    float pe = exp2f(score8(cur));
    pe = valid ? pe : 0.f;
    denom += pe;
#pragma unroll
    for (int j=0;j<8;j++) acc[j] = fmaf(pe, (float)cur.v[j], acc[j]);
  }

  // combine the two edge-slots
  denom += __shfl_xor(denom, 32);
  float inv = 1.f/denom;
#pragma unroll
  for (int j=0;j<8;j++){
    acc[j] += __shfl_xor(acc[j], 32);
    acc[j] *= inv;                       // per-head normalize (denom is per-head)
    acc[j] += __shfl_xor(acc[j], 4);     // mean over heads (head bits = 2,3,4)
    acc[j] += __shfl_xor(acc[j], 8);
    acc[j] += __shfl_xor(acc[j], 16);
  }
  if (lane < 4){
    float4 b0 = *(const float4*)(bias + lane*8);
    float4 b1 = *(const float4*)(bias + lane*8 + 4);
    float o[8];
    o[0]=acc[0]*0.125f+b0.x; o[1]=acc[1]*0.125f+b0.y;
    o[2]=acc[2]*0.125f+b0.z; o[3]=acc[3]*0.125f+b0.w;
    o[4]=acc[4]*0.125f+b1.x; o[5]=acc[5]*0.125f+b1.y;
    o[6]=acc[6]*0.125f+b1.z; o[7]=acc[7]*0.125f+b1.w;
    if (act){
#pragma unroll
      for (int j=0;j<8;j++) o[j] = lrelu(o[j], 0.01f);
    }
    float* po = out + (size_t)wid*CDIM + lane*8;
    *(float4*)(po)     = make_float4(o[0],o[1],o[2],o[3]);
    *(float4*)(po + 4) = make_float4(o[4],o[5],o[6],o[7]);
  }
}

extern "C" void kernel_launch(void* const* d_in, const int* in_sizes, int n_in,
                              void* d_out, int out_size, void* d_ws, size_t ws_size,
                              hipStream_t stream){
  (void)n_in; (void)out_size; (void)ws_size;
  const float* x    = (const float*)d_in[0];
  const int*   ei   = (const int*)d_in[1];
  const float* W1l  = (const float*)d_in[2];
  const float* b1l  = (const float*)d_in[3];
  const float* W1r  = (const float*)d_in[4];
  const float* b1r  = (const float*)d_in[5];
  const float* att1 = (const float*)d_in[6];
  const float* bias1= (const float*)d_in[7];
  const float* W2l  = (const float*)d_in[8];
  const float* b2l  = (const float*)d_in[9];
  const float* W2r  = (const float*)d_in[10];
  const float* b2r  = (const float*)d_in[11];
  const float* att2 = (const float*)d_in[12];
  const float* bias2= (const float*)d_in[13];
  int n = in_sizes[0] / 64;   // 50000
  int e = in_sizes[1] / 2;    // 800000
  const int* src = ei;
  const int* dst = ei + e;

  char* ws = (char*)d_ws;
  size_t off = 0;
  auto alloc = [&](size_t bytes)->char*{
    char* p = ws + off; off += (bytes + 255) & ~(size_t)255; return p;
  };
  _Float16* xl  = (_Float16*)alloc((size_t)n*ODIM*2);  // 25.6 MB fp16 (gather operand)
  float* xr     = (float*)alloc((size_t)n*ODIM*4);     // 51.2 MB fp32
  float* h      = (float*)alloc((size_t)n*CDIM*4);     // 6.4 MB layer-1 output
  int*   counts = (int*)alloc((size_t)n*4);
  int*   indptr = (int*)alloc((size_t)(n+1)*4);
  int*   cursor = (int*)alloc((size_t)n*4);
  int*   csr    = (int*)alloc((size_t)e*4);
  int*   bsums  = (int*)alloc((size_t)1024*4);

  int nblk = (n + 255) / 256;   // 196
  // deterministic init of everything the CSR pipeline reads (poison-proof)
  hipMemsetAsync(counts, 0, (size_t)n*4, stream);
  hipMemsetAsync(csr,    0, (size_t)e*4, stream);
  // CSR by dst (valid non-self edges only; self-loops handled in edge_kernel)
  count_kernel<<<(e+255)/256, 256, 0, stream>>>(src, dst, counts, e);
  block_sum_kernel<<<nblk, 256, 0, stream>>>(counts, bsums, n);
  scan_bsums_kernel<<<1, 1024, 0, stream>>>(bsums, nblk);
  local_scan_kernel<<<nblk, 256, 0, stream>>>(counts, bsums, indptr, cursor, n);
  scatter_kernel<<<(e+255)/256, 256, 0, stream>>>(src, dst, cursor, csr, e);

  int ntiles = (n + 63) / 64;   // 782
  // layer 1
  gemm_kernel<64><<<dim3(ntiles,4), 256, 0, stream>>>(x, W1l, b1l, W1r, b1r, xl, xr, n);
  edge_kernel<<<(n+3)/4, 256, 0, stream>>>(xl, xr, att1, bias1, indptr, csr, h, n, 1);
  // layer 2
  gemm_kernel<32><<<dim3(ntiles,4), 256, 0, stream>>>(h, W2l, b2l, W2r, b2r, xl, xr, n);
  edge_kernel<<<(n+3)/4, 256, 0, stream>>>(xl, xr, att2, bias2, indptr, csr, (float*)d_out, n, 0);
}

// Round 9
// 368.499 us; speedup vs baseline: 1.1427x; 1.1427x over previous
//
#include <hip/hip_runtime.h>
#include <math.h>

// GATv2 2-layer: N=50000, E=800000, HEADS=8, C=32, ODIM=256, IN_C=64
#define HEADS 8
#define CDIM 32
#define ODIM 256

typedef _Float16 h4 __attribute__((ext_vector_type(4)));

__device__ __forceinline__ float lrelu(float v, float s){ return fmaxf(v, s*v); }

// ---------------- CSR build ----------------
// count + rank in one pass: rank = position of edge within its dst bucket.
__global__ void count_kernel(const int* __restrict__ src, const int* __restrict__ dst,
                             int* __restrict__ counts, int* __restrict__ rank, int e){
  int i = blockIdx.x*256 + threadIdx.x;
  if (i < e){
    int s = src[i], d = dst[i];
    int r = -1;
    if (s != d) r = atomicAdd(counts + d, 1);   // src==dst originals masked (PyG removes them)
    rank[i] = r;
  }
}

// ---- 3-phase parallel scan ----
__global__ void block_sum_kernel(const int* __restrict__ counts, int* __restrict__ bsums, int n){
  int i = blockIdx.x*256 + threadIdx.x;
  int v = (i < n) ? counts[i] : 0;
#pragma unroll
  for (int off=1; off<64; off<<=1) v += __shfl_xor(v, off);
  __shared__ int ws[4];
  int lane = threadIdx.x & 63, w = threadIdx.x >> 6;
  if (lane == 0) ws[w] = v;
  __syncthreads();
  if (threadIdx.x == 0) bsums[blockIdx.x] = ws[0]+ws[1]+ws[2]+ws[3];
}

__global__ __launch_bounds__(1024) void scan_bsums_kernel(int* __restrict__ bsums, int nb){
  __shared__ int s[1024];
  int t = threadIdx.x;
  int v = (t < nb) ? bsums[t] : 0;
  s[t] = v;
  __syncthreads();
  for (int off=1; off<1024; off<<=1){
    int u = (t >= off) ? s[t-off] : 0;
    __syncthreads();
    s[t] += u;
    __syncthreads();
  }
  if (t < nb) bsums[t] = s[t] - v;   // exclusive
}

__global__ void local_scan_kernel(const int* __restrict__ counts, const int* __restrict__ bsums,
                                  int* __restrict__ indptr, int n){
  __shared__ int s[256];
  int t = threadIdx.x;
  int i = blockIdx.x*256 + t;
  int v = (i < n) ? counts[i] : 0;
  s[t] = v;
  __syncthreads();
  for (int off=1; off<256; off<<=1){
    int u = (t >= off) ? s[t-off] : 0;
    __syncthreads();
    s[t] += u;
    __syncthreads();
  }
  int excl = s[t] - v + bsums[blockIdx.x];
  if (i < n) indptr[i] = excl;
  if (i == n-1) indptr[n] = excl + v;
}

// atomic-free scatter: csr[indptr[d] + rank] = s. Ranks per dst are a
// permutation of 0..cnt-1 -> csr[beg,end) fully written (poison-proof).
__global__ void scatter_kernel(const int* __restrict__ src, const int* __restrict__ dst,
                               const int* __restrict__ rank, const int* __restrict__ indptr,
                               int* __restrict__ csr_src, int e){
  int i = blockIdx.x*256 + threadIdx.x;
  if (i < e){
    int r = rank[i];
    if (r >= 0){
      int d = dst[i];
      csr_src[indptr[d] + r] = src[i];
    }
  }
}

// ---------------- dense GEMM: out[n,o] = sum_k X[n,k]*W[o,k] + b[o] ----------------
// LDS-tiled, l+r fused (shares the x tile). Block = 64 nodes x 64 outputs,
// thread micro-tile = 4 nodes x 4 outputs x {l,r}. outl fp16 (gather operand),
// outr fp32. R4-R8 proven.
template<int K>
__global__ __launch_bounds__(256, 3) void gemm_kernel(const float* __restrict__ X,
    const float* __restrict__ Wl, const float* __restrict__ bl,
    const float* __restrict__ Wr, const float* __restrict__ br,
    _Float16* __restrict__ outl, float* __restrict__ outr, int n){
  const int KP = K + 4;
  __shared__ float xt[64*(K+4)];
  __shared__ float wt[2][64*(K+4)];
  int t = threadIdx.x;
  int n0 = blockIdx.x*64;
  int o0 = blockIdx.y*64;

  for (int idx = t; idx < 64*(K/4); idx += 256){
    int row = idx/(K/4), c = (idx%(K/4))*4;
    int node = n0 + row; if (node >= n) node = n-1;   // clamp; stores guarded
    float4 v = *(const float4*)(X + (size_t)node*K + c);
    *(float4*)(xt + row*KP + c) = v;
  }
  for (int idx = t; idx < 64*(K/4); idx += 256){
    int row = idx/(K/4), c = (idx%(K/4))*4;
    float4 vl = *(const float4*)(Wl + (size_t)(o0+row)*K + c);
    float4 vr = *(const float4*)(Wr + (size_t)(o0+row)*K + c);
    *(float4*)(wt[0] + row*KP + c) = vl;
    *(float4*)(wt[1] + row*KP + c) = vr;
  }
  __syncthreads();

  int og = t & 15;          // outputs o0 + og + 16j
  int ng = t >> 4;          // nodes   n0 + ng + 16i
  float accl[4][4] = {{0.f}}, accr[4][4] = {{0.f}};

#pragma unroll 2
  for (int kk = 0; kk < K; kk += 4){
    float4 xv[4], wl4[4], wr4[4];
#pragma unroll
    for (int i=0;i<4;i++) xv[i] = *(const float4*)(xt + (ng+16*i)*KP + kk);
#pragma unroll
    for (int j=0;j<4;j++){
      wl4[j] = *(const float4*)(wt[0] + (og+16*j)*KP + kk);
      wr4[j] = *(const float4*)(wt[1] + (og+16*j)*KP + kk);
    }
#pragma unroll
    for (int i=0;i<4;i++){
#pragma unroll
      for (int j=0;j<4;j++){
        accl[i][j] = fmaf(xv[i].x, wl4[j].x, fmaf(xv[i].y, wl4[j].y,
                     fmaf(xv[i].z, wl4[j].z, fmaf(xv[i].w, wl4[j].w, accl[i][j]))));
        accr[i][j] = fmaf(xv[i].x, wr4[j].x, fmaf(xv[i].y, wr4[j].y,
                     fmaf(xv[i].z, wr4[j].z, fmaf(xv[i].w, wr4[j].w, accr[i][j]))));
      }
    }
  }

  float bvl[4], bvr[4];
#pragma unroll
  for (int j=0;j<4;j++){ bvl[j] = bl[o0+og+16*j]; bvr[j] = br[o0+og+16*j]; }
#pragma unroll
  for (int i=0;i<4;i++){
    int node = n0 + ng + 16*i;
    if (node < n){
      _Float16* pl = outl + (size_t)node*ODIM + o0 + og;
      float*    pr = outr + (size_t)node*ODIM + o0 + og;
#pragma unroll
      for (int j=0;j<4;j++){
        pl[16*j] = (_Float16)(accl[i][j] + bvl[j]);
        pr[16*j] = accr[i][j] + bvr[j];
      }
    }
  }
}

// ---------------- fused edge softmax + aggregate, one wave per node ----------------
// R6-proven version. lane l: head h = l>>3, channels 4*(l&7)..+3 => h4 at
// half-offset 4*l (8B/lane, coalesced 512B/wave). exp2 without
// max-subtraction (scores ~N(0,1), fp32 exp2 overflow-safe), att pre-scaled
// by log2e. Depth-2 gather prefetch, guards read only written csr range.
__global__ __launch_bounds__(256) void edge_kernel(
    const _Float16* __restrict__ xl, const float* __restrict__ xr,
    const float* __restrict__ att, const float* __restrict__ bias,
    const int* __restrict__ indptr, const int* __restrict__ csr_src,
    float* __restrict__ out, int n, int act)
{
  int wid = blockIdx.x*4 + (threadIdx.x >> 6);
  if (wid >= n) return;
  int lane = threadIdx.x & 63;
  const float LOG2E = 1.44269504088896341f;
  float4 attv = *(const float4*)(att + 4*lane);
  attv.x *= LOG2E; attv.y *= LOG2E; attv.z *= LOG2E; attv.w *= LOG2E;
  float4 xr4  = *(const float4*)(xr + (size_t)wid*ODIM + 4*lane);
  h4 xvh = *(const h4*)(xl + (size_t)wid*ODIM + 4*lane);
  float4 xv = make_float4((float)xvh.x, (float)xvh.y, (float)xvh.z, (float)xvh.w);

  // self-loop seeds the accumulator (weight = exp2(s_self))
  float mx = lrelu(xv.x + xr4.x, 0.2f);
  float my = lrelu(xv.y + xr4.y, 0.2f);
  float mz = lrelu(xv.z + xr4.z, 0.2f);
  float mw = lrelu(xv.w + xr4.w, 0.2f);
  float p = mx*attv.x + my*attv.y + mz*attv.z + mw*attv.w;
  p += __shfl_xor(p, 1);
  p += __shfl_xor(p, 2);
  p += __shfl_xor(p, 4);
  float w0 = exp2f(p);
  float denom = w0;
  float4 acc = make_float4(w0*xv.x, w0*xv.y, w0*xv.z, w0*xv.w);

  int beg = __builtin_amdgcn_readfirstlane(indptr[wid]);
  int end = __builtin_amdgcn_readfirstlane(indptr[wid+1]);
  int cnt = end - beg;
  h4 r0 = {}, r1 = {};
  if (cnt > 0){
    int s0 = __builtin_amdgcn_readfirstlane(csr_src[beg]);
    r0 = *(const h4*)(xl + (size_t)s0*ODIM + 4*lane);
  }
  if (cnt > 1){
    int s1 = __builtin_amdgcn_readfirstlane(csr_src[beg+1]);
    r1 = *(const h4*)(xl + (size_t)s1*ODIM + 4*lane);
  }
  for (int k = 0; k < cnt; ++k){
    h4 curh = r0; r0 = r1;
    if (k+2 < cnt){
      int s2 = __builtin_amdgcn_readfirstlane(csr_src[beg+k+2]);
      r1 = *(const h4*)(xl + (size_t)s2*ODIM + 4*lane);   // prefetch 2 ahead
    }
    float cx = (float)curh.x, cy = (float)curh.y, cz = (float)curh.z, cw = (float)curh.w;
    float qx = lrelu(cx + xr4.x, 0.2f);
    float qy = lrelu(cy + xr4.y, 0.2f);
    float qz = lrelu(cz + xr4.z, 0.2f);
    float qw = lrelu(cw + xr4.w, 0.2f);
    float s = qx*attv.x + qy*attv.y + qz*attv.z + qw*attv.w;
    s += __shfl_xor(s, 1);
    s += __shfl_xor(s, 2);
    s += __shfl_xor(s, 4);
    float pe = exp2f(s);          // native v_exp_f32 (base-2), att pre-scaled
    denom += pe;
    acc.x = fmaf(pe, cx, acc.x);
    acc.y = fmaf(pe, cy, acc.y);
    acc.z = fmaf(pe, cz, acc.z);
    acc.w = fmaf(pe, cw, acc.w);
  }
  float inv = 1.f/denom;
  float vx = acc.x*inv, vy = acc.y*inv, vz = acc.z*inv, vw = acc.w*inv;
  // mean over heads: sum lanes {l, l^8, l^16, ...}
  vx += __shfl_xor(vx, 8);  vx += __shfl_xor(vx, 16);  vx += __shfl_xor(vx, 32);
  vy += __shfl_xor(vy, 8);  vy += __shfl_xor(vy, 16);  vy += __shfl_xor(vy, 32);
  vz += __shfl_xor(vz, 8);  vz += __shfl_xor(vz, 16);  vz += __shfl_xor(vz, 32);
  vw += __shfl_xor(vw, 8);  vw += __shfl_xor(vw, 16);  vw += __shfl_xor(vw, 32);
  if (lane < 8){
    float4 bv = *(const float4*)(bias + 4*lane);
    float ox = vx*0.125f + bv.x;
    float oy = vy*0.125f + bv.y;
    float oz = vz*0.125f + bv.z;
    float ow = vw*0.125f + bv.w;
    if (act){
      ox = lrelu(ox, 0.01f); oy = lrelu(oy, 0.01f);
      oz = lrelu(oz, 0.01f); ow = lrelu(ow, 0.01f);
    }
    *(float4*)(out + (size_t)wid*CDIM + 4*lane) = make_float4(ox, oy, oz, ow);
  }
}

extern "C" void kernel_launch(void* const* d_in, const int* in_sizes, int n_in,
                              void* d_out, int out_size, void* d_ws, size_t ws_size,
                              hipStream_t stream){
  (void)n_in; (void)out_size; (void)ws_size;
  const float* x    = (const float*)d_in[0];
  const int*   ei   = (const int*)d_in[1];
  const float* W1l  = (const float*)d_in[2];
  const float* b1l  = (const float*)d_in[3];
  const float* W1r  = (const float*)d_in[4];
  const float* b1r  = (const float*)d_in[5];
  const float* att1 = (const float*)d_in[6];
  const float* bias1= (const float*)d_in[7];
  const float* W2l  = (const float*)d_in[8];
  const float* b2l  = (const float*)d_in[9];
  const float* W2r  = (const float*)d_in[10];
  const float* b2r  = (const float*)d_in[11];
  const float* att2 = (const float*)d_in[12];
  const float* bias2= (const float*)d_in[13];
  int n = in_sizes[0] / 64;   // 50000
  int e = in_sizes[1] / 2;    // 800000
  const int* src = ei;
  const int* dst = ei + e;

  char* ws = (char*)d_ws;
  size_t off = 0;
  auto alloc = [&](size_t bytes)->char*{
    char* p = ws + off; off += (bytes + 255) & ~(size_t)255; return p;
  };
  _Float16* xl  = (_Float16*)alloc((size_t)n*ODIM*2);  // 25.6 MB fp16 (gather operand)
  float* xr     = (float*)alloc((size_t)n*ODIM*4);     // 51.2 MB fp32
  float* h      = (float*)alloc((size_t)n*CDIM*4);     // 6.4 MB layer-1 output
  int*   counts = (int*)alloc((size_t)n*4);
  int*   indptr = (int*)alloc((size_t)(n+1)*4);
  int*   rank   = (int*)alloc((size_t)e*4);
  int*   csr    = (int*)alloc((size_t)e*4);
  int*   bsums  = (int*)alloc((size_t)1024*4);

  int nblk = (n + 255) / 256;   // 196
  hipMemsetAsync(counts, 0, (size_t)n*4, stream);
  // CSR by dst (valid non-self edges only; self-loops handled in edge_kernel)
  count_kernel<<<(e+255)/256, 256, 0, stream>>>(src, dst, counts, rank, e);
  block_sum_kernel<<<nblk, 256, 0, stream>>>(counts, bsums, n);
  scan_bsums_kernel<<<1, 1024, 0, stream>>>(bsums, nblk);
  local_scan_kernel<<<nblk, 256, 0, stream>>>(counts, bsums, indptr, n);
  scatter_kernel<<<(e+255)/256, 256, 0, stream>>>(src, dst, rank, indptr, csr, e);

  int ntiles = (n + 63) / 64;   // 782
  // layer 1
  gemm_kernel<64><<<dim3(ntiles,4), 256, 0, stream>>>(x, W1l, b1l, W1r, b1r, xl, xr, n);
  edge_kernel<<<(n+3)/4, 256, 0, stream>>>(xl, xr, att1, bias1, indptr, csr, h, n, 1);
  // layer 2
  gemm_kernel<32><<<dim3(ntiles,4), 256, 0, stream>>>(h, W2l, b2l, W2r, b2r, xl, xr, n);
  edge_kernel<<<(n+3)/4, 256, 0, stream>>>(xl, xr, att2, bias2, indptr, csr, (float*)d_out, n, 0);
}

// Round 10
// 354.291 us; speedup vs baseline: 1.1886x; 1.0401x over previous
//
#include <hip/hip_runtime.h>
#include <math.h>

// GATv2 2-layer: N=50000, E=800000, HEADS=8, C=32, ODIM=256, IN_C=64
#define HEADS 8
#define CDIM 32
#define ODIM 256

typedef _Float16 h2 __attribute__((ext_vector_type(2)));
typedef _Float16 h4 __attribute__((ext_vector_type(4)));
union H4 { h4 v; h2 p[2]; };

#if __has_builtin(__builtin_amdgcn_fdot2)
#define FDOT2(a,b,c) __builtin_amdgcn_fdot2((a),(b),(c),false)
#else
static __device__ __forceinline__ float fdot2_sw(h2 a, h2 b, float c){
  return fmaf((float)a.x, (float)b.x, fmaf((float)a.y, (float)b.y, c));
}
#define FDOT2(a,b,c) fdot2_sw((a),(b),(c))
#endif

__device__ __forceinline__ float lrelu(float v, float s){ return fmaxf(v, s*v); }

// ---- 3-phase parallel scan ----
__global__ void block_sum_kernel(const int* __restrict__ counts, int* __restrict__ bsums, int n){
  int i = blockIdx.x*256 + threadIdx.x;
  int v = (i < n) ? counts[i] : 0;
#pragma unroll
  for (int off=1; off<64; off<<=1) v += __shfl_xor(v, off);
  __shared__ int ws[4];
  int lane = threadIdx.x & 63, w = threadIdx.x >> 6;
  if (lane == 0) ws[w] = v;
  __syncthreads();
  if (threadIdx.x == 0) bsums[blockIdx.x] = ws[0]+ws[1]+ws[2]+ws[3];
}

__global__ __launch_bounds__(1024) void scan_bsums_kernel(int* __restrict__ bsums, int nb){
  __shared__ int s[1024];
  int t = threadIdx.x;
  int v = (t < nb) ? bsums[t] : 0;
  s[t] = v;
  __syncthreads();
  for (int off=1; off<1024; off<<=1){
    int u = (t >= off) ? s[t-off] : 0;
    __syncthreads();
    s[t] += u;
    __syncthreads();
  }
  if (t < nb) bsums[t] = s[t] - v;   // exclusive
}

__global__ void local_scan_kernel(const int* __restrict__ counts, const int* __restrict__ bsums,
                                  int* __restrict__ indptr, int n){
  __shared__ int s[256];
  int t = threadIdx.x;
  int i = blockIdx.x*256 + t;
  int v = (i < n) ? counts[i] : 0;
  s[t] = v;
  __syncthreads();
  for (int off=1; off<256; off<<=1){
    int u = (t >= off) ? s[t-off] : 0;
    __syncthreads();
    s[t] += u;
    __syncthreads();
  }
  int excl = s[t] - v + bsums[blockIdx.x];
  if (i < n) indptr[i] = excl;
  if (i == n-1) indptr[n] = excl + v;
}

// atomic-free scatter: csr[indptr[d] + rank] = s. Ranks per dst are a
// permutation of 0..cnt-1 -> csr[beg,end) fully written (poison-proof).
__global__ void scatter_kernel(const int* __restrict__ src, const int* __restrict__ dst,
                               const int* __restrict__ rank, const int* __restrict__ indptr,
                               int* __restrict__ csr_src, int e){
  int i = blockIdx.x*256 + threadIdx.x;
  if (i < e){
    int r = rank[i];
    if (r >= 0){
      int d = dst[i];
      csr_src[indptr[d] + r] = src[i];
    }
  }
}

// ---------------- dense GEMM: out[n,o] = sum_k X[n,k]*W[o,k] + b[o] ----------------
// LDS-tiled, l+r fused. Block = 64 nodes x 64 outputs, micro-tile 4x4x{l,r}.
// outl fp16 (gather operand), outr fp32. R4-R9 proven.
// FUSE_COUNT: blockIdx.y==4 blocks instead run the independent CSR count+rank
// pass (grid-stride) — hides it under the GEMM on the critical path.
template<int K, bool FUSE_COUNT>
__global__ __launch_bounds__(256, 3) void gemm_kernel(const float* __restrict__ X,
    const float* __restrict__ Wl, const float* __restrict__ bl,
    const float* __restrict__ Wr, const float* __restrict__ br,
    _Float16* __restrict__ outl, float* __restrict__ outr, int n,
    const int* __restrict__ src, const int* __restrict__ dst,
    int* __restrict__ counts, int* __restrict__ rank, int e){
  if (FUSE_COUNT && blockIdx.y == 4){
    int stride = gridDim.x*256;
    for (int i = blockIdx.x*256 + threadIdx.x; i < e; i += stride){
      int s = src[i], d = dst[i];
      int r = -1;
      if (s != d) r = atomicAdd(counts + d, 1);   // src==dst masked (PyG removes them)
      rank[i] = r;
    }
    return;
  }
  const int KP = K + 4;
  __shared__ float xt[64*(K+4)];
  __shared__ float wt[2][64*(K+4)];
  int t = threadIdx.x;
  int n0 = blockIdx.x*64;
  int o0 = blockIdx.y*64;

  for (int idx = t; idx < 64*(K/4); idx += 256){
    int row = idx/(K/4), c = (idx%(K/4))*4;
    int node = n0 + row; if (node >= n) node = n-1;   // clamp; stores guarded
    float4 v = *(const float4*)(X + (size_t)node*K + c);
    *(float4*)(xt + row*KP + c) = v;
  }
  for (int idx = t; idx < 64*(K/4); idx += 256){
    int row = idx/(K/4), c = (idx%(K/4))*4;
    float4 vl = *(const float4*)(Wl + (size_t)(o0+row)*K + c);
    float4 vr = *(const float4*)(Wr + (size_t)(o0+row)*K + c);
    *(float4*)(wt[0] + row*KP + c) = vl;
    *(float4*)(wt[1] + row*KP + c) = vr;
  }
  __syncthreads();

  int og = t & 15;          // outputs o0 + og + 16j
  int ng = t >> 4;          // nodes   n0 + ng + 16i
  float accl[4][4] = {{0.f}}, accr[4][4] = {{0.f}};

#pragma unroll 2
  for (int kk = 0; kk < K; kk += 4){
    float4 xv[4], wl4[4], wr4[4];
#pragma unroll
    for (int i=0;i<4;i++) xv[i] = *(const float4*)(xt + (ng+16*i)*KP + kk);
#pragma unroll
    for (int j=0;j<4;j++){
      wl4[j] = *(const float4*)(wt[0] + (og+16*j)*KP + kk);
      wr4[j] = *(const float4*)(wt[1] + (og+16*j)*KP + kk);
    }
#pragma unroll
    for (int i=0;i<4;i++){
#pragma unroll
      for (int j=0;j<4;j++){
        accl[i][j] = fmaf(xv[i].x, wl4[j].x, fmaf(xv[i].y, wl4[j].y,
                     fmaf(xv[i].z, wl4[j].z, fmaf(xv[i].w, wl4[j].w, accl[i][j]))));
        accr[i][j] = fmaf(xv[i].x, wr4[j].x, fmaf(xv[i].y, wr4[j].y,
                     fmaf(xv[i].z, wr4[j].z, fmaf(xv[i].w, wr4[j].w, accr[i][j]))));
      }
    }
  }

  float bvl[4], bvr[4];
#pragma unroll
  for (int j=0;j<4;j++){ bvl[j] = bl[o0+og+16*j]; bvr[j] = br[o0+og+16*j]; }
#pragma unroll
  for (int i=0;i<4;i++){
    int node = n0 + ng + 16*i;
    if (node < n){
      _Float16* pl = outl + (size_t)node*ODIM + o0 + og;
      float*    pr = outr + (size_t)node*ODIM + o0 + og;
#pragma unroll
      for (int j=0;j<4;j++){
        pl[16*j] = (_Float16)(accl[i][j] + bvl[j]);
        pr[16*j] = accr[i][j] + bvr[j];
      }
    }
  }
}

// ---------------- fused edge softmax + aggregate, one wave per node ----------------
// R6-proven memory structure (1 edge/iter, depth-2 guarded prefetch, h4/lane
// coalesced 512B/wave) + R7-proven packed-fp16 score path:
// score = fdot2(max(t,0.2t), att*log2e) over 2 h2 pairs, reduce over 3 lane
// bits; exp2 without max-subtraction (scores ~N(0,1), fp32 exp2 safe).
// Aggregation via single-use (float)h16 inside fmaf -> v_fma_mix.
__global__ __launch_bounds__(256) void edge_kernel(
    const _Float16* __restrict__ xl, const float* __restrict__ xr,
    const float* __restrict__ att, const float* __restrict__ bias,
    const int* __restrict__ indptr, const int* __restrict__ csr_src,
    float* __restrict__ out, int n, int act)
{
  int wid = blockIdx.x*4 + (threadIdx.x >> 6);
  if (wid >= n) return;
  int lane = threadIdx.x & 63;
  const float LOG2E = 1.44269504088896341f;

  float4 attf = *(const float4*)(att + 4*lane);
  h2 at0 = (h2){(_Float16)(attf.x*LOG2E), (_Float16)(attf.y*LOG2E)};
  h2 at1 = (h2){(_Float16)(attf.z*LOG2E), (_Float16)(attf.w*LOG2E)};
  const h2 c02 = {(_Float16)0.2f, (_Float16)0.2f};

  float4 xr4 = *(const float4*)(xr + (size_t)wid*ODIM + 4*lane);
  H4 xrh;
  xrh.p[0] = (h2){(_Float16)xr4.x, (_Float16)xr4.y};
  xrh.p[1] = (h2){(_Float16)xr4.z, (_Float16)xr4.w};

  H4 self; self.v = *(const h4*)(xl + (size_t)wid*ODIM + 4*lane);

  auto score = [&](const H4& c)->float{
    h2 t0 = c.p[0] + xrh.p[0];
    h2 t1 = c.p[1] + xrh.p[1];
    h2 q0 = __builtin_elementwise_max(t0, t0 * c02);
    h2 q1 = __builtin_elementwise_max(t1, t1 * c02);
    float d = FDOT2(q0, at0, FDOT2(q1, at1, 0.f));
    d += __shfl_xor(d, 1);   // reduce over the 8 lanes of this head
    d += __shfl_xor(d, 2);
    d += __shfl_xor(d, 4);
    return d;
  };

  // self-loop seeds the accumulator
  float w0 = exp2f(score(self));
  float denom = w0;
  float4 acc;
  acc.x = w0 * (float)self.v.x;
  acc.y = w0 * (float)self.v.y;
  acc.z = w0 * (float)self.v.z;
  acc.w = w0 * (float)self.v.w;

  int beg = __builtin_amdgcn_readfirstlane(indptr[wid]);
  int end = __builtin_amdgcn_readfirstlane(indptr[wid+1]);
  int cnt = end - beg;
  H4 r0, r1;
  r0.v = (h4){}; r1.v = (h4){};
  if (cnt > 0){
    int s0 = __builtin_amdgcn_readfirstlane(csr_src[beg]);
    r0.v = *(const h4*)(xl + (size_t)s0*ODIM + 4*lane);
  }
  if (cnt > 1){
    int s1 = __builtin_amdgcn_readfirstlane(csr_src[beg+1]);
    r1.v = *(const h4*)(xl + (size_t)s1*ODIM + 4*lane);
  }
  for (int k = 0; k < cnt; ++k){
    H4 cur = r0; r0 = r1;
    if (k+2 < cnt){
      int s2 = __builtin_amdgcn_readfirstlane(csr_src[beg+k+2]);
      r1.v = *(const h4*)(xl + (size_t)s2*ODIM + 4*lane);   // prefetch 2 ahead
    }
    float pe = exp2f(score(cur));
    denom += pe;
    acc.x = fmaf(pe, (float)cur.v.x, acc.x);   // v_fma_mix (single-use cvt)
    acc.y = fmaf(pe, (float)cur.v.y, acc.y);
    acc.z = fmaf(pe, (float)cur.v.z, acc.z);
    acc.w = fmaf(pe, (float)cur.v.w, acc.w);
  }
  float inv = 1.f/denom;
  float vx = acc.x*inv, vy = acc.y*inv, vz = acc.z*inv, vw = acc.w*inv;
  // mean over heads: sum lanes {l, l^8, l^16, l^32}
  vx += __shfl_xor(vx, 8);  vx += __shfl_xor(vx, 16);  vx += __shfl_xor(vx, 32);
  vy += __shfl_xor(vy, 8);  vy += __shfl_xor(vy, 16);  vy += __shfl_xor(vy, 32);
  vz += __shfl_xor(vz, 8);  vz += __shfl_xor(vz, 16);  vz += __shfl_xor(vz, 32);
  vw += __shfl_xor(vw, 8);  vw += __shfl_xor(vw, 16);  vw += __shfl_xor(vw, 32);
  if (lane < 8){
    float4 bv = *(const float4*)(bias + 4*lane);
    float ox = vx*0.125f + bv.x;
    float oy = vy*0.125f + bv.y;
    float oz = vz*0.125f + bv.z;
    float ow = vw*0.125f + bv.w;
    if (act){
      ox = lrelu(ox, 0.01f); oy = lrelu(oy, 0.01f);
      oz = lrelu(oz, 0.01f); ow = lrelu(ow, 0.01f);
    }
    *(float4*)(out + (size_t)wid*CDIM + 4*lane) = make_float4(ox, oy, oz, ow);
  }
}

extern "C" void kernel_launch(void* const* d_in, const int* in_sizes, int n_in,
                              void* d_out, int out_size, void* d_ws, size_t ws_size,
                              hipStream_t stream){
  (void)n_in; (void)out_size; (void)ws_size;
  const float* x    = (const float*)d_in[0];
  const int*   ei   = (const int*)d_in[1];
  const float* W1l  = (const float*)d_in[2];
  const float* b1l  = (const float*)d_in[3];
  const float* W1r  = (const float*)d_in[4];
  const float* b1r  = (const float*)d_in[5];
  const float* att1 = (const float*)d_in[6];
  const float* bias1= (const float*)d_in[7];
  const float* W2l  = (const float*)d_in[8];
  const float* b2l  = (const float*)d_in[9];
  const float* W2r  = (const float*)d_in[10];
  const float* b2r  = (const float*)d_in[11];
  const float* att2 = (const float*)d_in[12];
  const float* bias2= (const float*)d_in[13];
  int n = in_sizes[0] / 64;   // 50000
  int e = in_sizes[1] / 2;    // 800000
  const int* src = ei;
  const int* dst = ei + e;

  char* ws = (char*)d_ws;
  size_t off = 0;
  auto alloc = [&](size_t bytes)->char*{
    char* p = ws + off; off += (bytes + 255) & ~(size_t)255; return p;
  };
  _Float16* xl  = (_Float16*)alloc((size_t)n*ODIM*2);  // 25.6 MB fp16 (gather operand)
  float* xr     = (float*)alloc((size_t)n*ODIM*4);     // 51.2 MB fp32
  float* h      = (float*)alloc((size_t)n*CDIM*4);     // 6.4 MB layer-1 output
  int*   counts = (int*)alloc((size_t)n*4);
  int*   indptr = (int*)alloc((size_t)(n+1)*4);
  int*   rank   = (int*)alloc((size_t)e*4);
  int*   csr    = (int*)alloc((size_t)e*4);
  int*   bsums  = (int*)alloc((size_t)1024*4);

  int nblk = (n + 255) / 256;   // 196
  int ntiles = (n + 63) / 64;   // 782
  hipMemsetAsync(counts, 0, (size_t)n*4, stream);

  // layer-1 GEMM with fused CSR count (blockIdx.y==4 slice)
  gemm_kernel<64,true><<<dim3(ntiles,5), 256, 0, stream>>>(
      x, W1l, b1l, W1r, b1r, xl, xr, n, src, dst, counts, rank, e);
  block_sum_kernel<<<nblk, 256, 0, stream>>>(counts, bsums, n);
  scan_bsums_kernel<<<1, 1024, 0, stream>>>(bsums, nblk);
  local_scan_kernel<<<nblk, 256, 0, stream>>>(counts, bsums, indptr, n);
  scatter_kernel<<<(e+255)/256, 256, 0, stream>>>(src, dst, rank, indptr, csr, e);

  edge_kernel<<<(n+3)/4, 256, 0, stream>>>(xl, xr, att1, bias1, indptr, csr, h, n, 1);
  // layer 2
  gemm_kernel<32,false><<<dim3(ntiles,4), 256, 0, stream>>>(
      h, W2l, b2l, W2r, b2r, xl, xr, n, nullptr, nullptr, nullptr, nullptr, 0);
  edge_kernel<<<(n+3)/4, 256, 0, stream>>>(xl, xr, att2, bias2, indptr, csr, (float*)d_out, n, 0);
}

// Round 11
// 331.104 us; speedup vs baseline: 1.2718x; 1.0700x over previous
//
#include <hip/hip_runtime.h>
#include <math.h>

// GATv2 2-layer: N=50000, E=800000, HEADS=8, C=32, ODIM=256, IN_C=64
#define HEADS 8
#define CDIM 32
#define ODIM 256

typedef _Float16 h2 __attribute__((ext_vector_type(2)));
typedef _Float16 h4 __attribute__((ext_vector_type(4)));
union H4 { h4 v; h2 p[2]; };

#if __has_builtin(__builtin_amdgcn_fdot2)
#define FDOT2(a,b,c) __builtin_amdgcn_fdot2((a),(b),(c),false)
#else
static __device__ __forceinline__ float fdot2_sw(h2 a, h2 b, float c){
  return fmaf((float)a.x, (float)b.x, fmaf((float)a.y, (float)b.y, c));
}
#define FDOT2(a,b,c) fdot2_sw((a),(b),(c))
#endif

__device__ __forceinline__ float lrelu(float v, float s){ return fmaxf(v, s*v); }

// ---- 3-phase parallel scan ----
__global__ void block_sum_kernel(const int* __restrict__ counts, int* __restrict__ bsums, int n){
  int i = blockIdx.x*256 + threadIdx.x;
  int v = (i < n) ? counts[i] : 0;
#pragma unroll
  for (int off=1; off<64; off<<=1) v += __shfl_xor(v, off);
  __shared__ int ws[4];
  int lane = threadIdx.x & 63, w = threadIdx.x >> 6;
  if (lane == 0) ws[w] = v;
  __syncthreads();
  if (threadIdx.x == 0) bsums[blockIdx.x] = ws[0]+ws[1]+ws[2]+ws[3];
}

__global__ __launch_bounds__(1024) void scan_bsums_kernel(int* __restrict__ bsums, int nb){
  __shared__ int s[1024];
  int t = threadIdx.x;
  int v = (t < nb) ? bsums[t] : 0;
  s[t] = v;
  __syncthreads();
  for (int off=1; off<1024; off<<=1){
    int u = (t >= off) ? s[t-off] : 0;
    __syncthreads();
    s[t] += u;
    __syncthreads();
  }
  if (t < nb) bsums[t] = s[t] - v;   // exclusive
}

__global__ void local_scan_kernel(const int* __restrict__ counts, const int* __restrict__ bsums,
                                  int* __restrict__ indptr, int n){
  __shared__ int s[256];
  int t = threadIdx.x;
  int i = blockIdx.x*256 + t;
  int v = (i < n) ? counts[i] : 0;
  s[t] = v;
  __syncthreads();
  for (int off=1; off<256; off<<=1){
    int u = (t >= off) ? s[t-off] : 0;
    __syncthreads();
    s[t] += u;
    __syncthreads();
  }
  int excl = s[t] - v + bsums[blockIdx.x];
  if (i < n) indptr[i] = excl;
  if (i == n-1) indptr[n] = excl + v;
}

// atomic-free scatter: csr[indptr[d] + rank] = s. Ranks per dst are a
// permutation of 0..cnt-1 -> csr[beg,end) fully written (poison-proof).
__global__ void scatter_kernel(const int* __restrict__ src, const int* __restrict__ dst,
                               const int* __restrict__ rank, const int* __restrict__ indptr,
                               int* __restrict__ csr_src, int e){
  int i = blockIdx.x*256 + threadIdx.x;
  if (i < e){
    int r = rank[i];
    if (r >= 0){
      int d = dst[i];
      csr_src[indptr[d] + r] = src[i];
    }
  }
}

// ---------------- dense GEMM: out[n,o] = sum_k X[n,k]*W[o,k] + b[o] ----------------
// LDS-tiled, l+r fused. Block = 64 nodes x 64 outputs, micro-tile 4x4x{l,r}.
// Both outputs fp16 (edge kernel consumes fp16 for score AND aggregate —
// storing fp16 here is numerically identical to converting in the edge).
// FUSE_COUNT: blockIdx.y==0, x<96 blocks run the independent CSR count+rank
// pass concurrently with the GEMM (y==0 dispatches FIRST, x-fastest order;
// the other y==0 blocks no-op instantly so GEMM blocks backfill the CUs).
template<int K, bool FUSE_COUNT>
__global__ __launch_bounds__(256, 3) void gemm_kernel(const float* __restrict__ X,
    const float* __restrict__ Wl, const float* __restrict__ bl,
    const float* __restrict__ Wr, const float* __restrict__ br,
    _Float16* __restrict__ outl, _Float16* __restrict__ outr, int n,
    const int* __restrict__ src, const int* __restrict__ dst,
    int* __restrict__ counts, int* __restrict__ rank, int e){
  if (FUSE_COUNT && blockIdx.y == 0){
    const int CB = 96;
    if (blockIdx.x < CB){
      int stride = CB*256;
      for (int i = blockIdx.x*256 + threadIdx.x; i < e; i += stride){
        int s = src[i], d = dst[i];
        int r = -1;
        if (s != d) r = atomicAdd(counts + d, 1);   // src==dst masked (PyG removes)
        rank[i] = r;
      }
    }
    return;
  }
  const int KP = K + 4;
  __shared__ float xt[64*(K+4)];
  __shared__ float wt[2][64*(K+4)];
  int t = threadIdx.x;
  int n0 = blockIdx.x*64;
  int o0 = (FUSE_COUNT ? (blockIdx.y-1) : blockIdx.y)*64;

  for (int idx = t; idx < 64*(K/4); idx += 256){
    int row = idx/(K/4), c = (idx%(K/4))*4;
    int node = n0 + row; if (node >= n) node = n-1;   // clamp; stores guarded
    float4 v = *(const float4*)(X + (size_t)node*K + c);
    *(float4*)(xt + row*KP + c) = v;
  }
  for (int idx = t; idx < 64*(K/4); idx += 256){
    int row = idx/(K/4), c = (idx%(K/4))*4;
    float4 vl = *(const float4*)(Wl + (size_t)(o0+row)*K + c);
    float4 vr = *(const float4*)(Wr + (size_t)(o0+row)*K + c);
    *(float4*)(wt[0] + row*KP + c) = vl;
    *(float4*)(wt[1] + row*KP + c) = vr;
  }
  __syncthreads();

  int og = t & 15;          // outputs o0 + og + 16j
  int ng = t >> 4;          // nodes   n0 + ng + 16i
  float accl[4][4] = {{0.f}}, accr[4][4] = {{0.f}};

#pragma unroll 2
  for (int kk = 0; kk < K; kk += 4){
    float4 xv[4], wl4[4], wr4[4];
#pragma unroll
    for (int i=0;i<4;i++) xv[i] = *(const float4*)(xt + (ng+16*i)*KP + kk);
#pragma unroll
    for (int j=0;j<4;j++){
      wl4[j] = *(const float4*)(wt[0] + (og+16*j)*KP + kk);
      wr4[j] = *(const float4*)(wt[1] + (og+16*j)*KP + kk);
    }
#pragma unroll
    for (int i=0;i<4;i++){
#pragma unroll
      for (int j=0;j<4;j++){
        accl[i][j] = fmaf(xv[i].x, wl4[j].x, fmaf(xv[i].y, wl4[j].y,
                     fmaf(xv[i].z, wl4[j].z, fmaf(xv[i].w, wl4[j].w, accl[i][j]))));
        accr[i][j] = fmaf(xv[i].x, wr4[j].x, fmaf(xv[i].y, wr4[j].y,
                     fmaf(xv[i].z, wr4[j].z, fmaf(xv[i].w, wr4[j].w, accr[i][j]))));
      }
    }
  }

  float bvl[4], bvr[4];
#pragma unroll
  for (int j=0;j<4;j++){ bvl[j] = bl[o0+og+16*j]; bvr[j] = br[o0+og+16*j]; }
#pragma unroll
  for (int i=0;i<4;i++){
    int node = n0 + ng + 16*i;
    if (node < n){
      _Float16* pl = outl + (size_t)node*ODIM + o0 + og;
      _Float16* pr = outr + (size_t)node*ODIM + o0 + og;
#pragma unroll
      for (int j=0;j<4;j++){
        pl[16*j] = (_Float16)(accl[i][j] + bvl[j]);
        pr[16*j] = (_Float16)(accr[i][j] + bvr[j]);
      }
    }
  }
}

// ---------------- fused edge softmax + aggregate, one wave per node ----------------
// R6-proven memory structure (1 edge/iter, depth-2 guarded prefetch, h4/lane
// coalesced 512B/wave) + packed-fp16 score path (R10-proven):
// score = fdot2(max(t,0.2t), att*log2e); exp2 without max-subtraction
// (scores ~N(0,1), fp32 exp2 safe). xr now stored fp16 by the GEMM —
// identical numerics to the previous in-kernel conversion.
__global__ __launch_bounds__(256) void edge_kernel(
    const _Float16* __restrict__ xl, const _Float16* __restrict__ xr,
    const float* __restrict__ att, const float* __restrict__ bias,
    const int* __restrict__ indptr, const int* __restrict__ csr_src,
    float* __restrict__ out, int n, int act)
{
  int wid = blockIdx.x*4 + (threadIdx.x >> 6);
  if (wid >= n) return;
  int lane = threadIdx.x & 63;
  const float LOG2E = 1.44269504088896341f;

  float4 attf = *(const float4*)(att + 4*lane);
  h2 at0 = (h2){(_Float16)(attf.x*LOG2E), (_Float16)(attf.y*LOG2E)};
  h2 at1 = (h2){(_Float16)(attf.z*LOG2E), (_Float16)(attf.w*LOG2E)};
  const h2 c02 = {(_Float16)0.2f, (_Float16)0.2f};

  H4 xrh; xrh.v = *(const h4*)(xr + (size_t)wid*ODIM + 4*lane);
  H4 self; self.v = *(const h4*)(xl + (size_t)wid*ODIM + 4*lane);

  auto score = [&](const H4& c)->float{
    h2 t0 = c.p[0] + xrh.p[0];
    h2 t1 = c.p[1] + xrh.p[1];
    h2 q0 = __builtin_elementwise_max(t0, t0 * c02);
    h2 q1 = __builtin_elementwise_max(t1, t1 * c02);
    float d = FDOT2(q0, at0, FDOT2(q1, at1, 0.f));
    d += __shfl_xor(d, 1);   // reduce over the 8 lanes of this head
    d += __shfl_xor(d, 2);
    d += __shfl_xor(d, 4);
    return d;
  };

  // self-loop seeds the accumulator
  float w0 = exp2f(score(self));
  float denom = w0;
  float4 acc;
  acc.x = w0 * (float)self.v.x;
  acc.y = w0 * (float)self.v.y;
  acc.z = w0 * (float)self.v.z;
  acc.w = w0 * (float)self.v.w;

  int beg = __builtin_amdgcn_readfirstlane(indptr[wid]);
  int end = __builtin_amdgcn_readfirstlane(indptr[wid+1]);
  int cnt = end - beg;
  H4 r0, r1;
  r0.v = (h4){}; r1.v = (h4){};
  if (cnt > 0){
    int s0 = __builtin_amdgcn_readfirstlane(csr_src[beg]);
    r0.v = *(const h4*)(xl + (size_t)s0*ODIM + 4*lane);
  }
  if (cnt > 1){
    int s1 = __builtin_amdgcn_readfirstlane(csr_src[beg+1]);
    r1.v = *(const h4*)(xl + (size_t)s1*ODIM + 4*lane);
  }
  for (int k = 0; k < cnt; ++k){
    H4 cur = r0; r0 = r1;
    if (k+2 < cnt){
      int s2 = __builtin_amdgcn_readfirstlane(csr_src[beg+k+2]);
      r1.v = *(const h4*)(xl + (size_t)s2*ODIM + 4*lane);   // prefetch 2 ahead
    }
    float pe = exp2f(score(cur));
    denom += pe;
    acc.x = fmaf(pe, (float)cur.v.x, acc.x);   // v_fma_mix (single-use cvt)
    acc.y = fmaf(pe, (float)cur.v.y, acc.y);
    acc.z = fmaf(pe, (float)cur.v.z, acc.z);
    acc.w = fmaf(pe, (float)cur.v.w, acc.w);
  }
  float inv = 1.f/denom;
  float vx = acc.x*inv, vy = acc.y*inv, vz = acc.z*inv, vw = acc.w*inv;
  // mean over heads: sum lanes {l, l^8, l^16, l^32}
  vx += __shfl_xor(vx, 8);  vx += __shfl_xor(vx, 16);  vx += __shfl_xor(vx, 32);
  vy += __shfl_xor(vy, 8);  vy += __shfl_xor(vy, 16);  vy += __shfl_xor(vy, 32);
  vz += __shfl_xor(vz, 8);  vz += __shfl_xor(vz, 16);  vz += __shfl_xor(vz, 32);
  vw += __shfl_xor(vw, 8);  vw += __shfl_xor(vw, 16);  vw += __shfl_xor(vw, 32);
  if (lane < 8){
    float4 bv = *(const float4*)(bias + 4*lane);
    float ox = vx*0.125f + bv.x;
    float oy = vy*0.125f + bv.y;
    float oz = vz*0.125f + bv.z;
    float ow = vw*0.125f + bv.w;
    if (act){
      ox = lrelu(ox, 0.01f); oy = lrelu(oy, 0.01f);
      oz = lrelu(oz, 0.01f); ow = lrelu(ow, 0.01f);
    }
    *(float4*)(out + (size_t)wid*CDIM + 4*lane) = make_float4(ox, oy, oz, ow);
  }
}

extern "C" void kernel_launch(void* const* d_in, const int* in_sizes, int n_in,
                              void* d_out, int out_size, void* d_ws, size_t ws_size,
                              hipStream_t stream){
  (void)n_in; (void)out_size; (void)ws_size;
  const float* x    = (const float*)d_in[0];
  const int*   ei   = (const int*)d_in[1];
  const float* W1l  = (const float*)d_in[2];
  const float* b1l  = (const float*)d_in[3];
  const float* W1r  = (const float*)d_in[4];
  const float* b1r  = (const float*)d_in[5];
  const float* att1 = (const float*)d_in[6];
  const float* bias1= (const float*)d_in[7];
  const float* W2l  = (const float*)d_in[8];
  const float* b2l  = (const float*)d_in[9];
  const float* W2r  = (const float*)d_in[10];
  const float* b2r  = (const float*)d_in[11];
  const float* att2 = (const float*)d_in[12];
  const float* bias2= (const float*)d_in[13];
  int n = in_sizes[0] / 64;   // 50000
  int e = in_sizes[1] / 2;    // 800000
  const int* src = ei;
  const int* dst = ei + e;

  char* ws = (char*)d_ws;
  size_t off = 0;
  auto alloc = [&](size_t bytes)->char*{
    char* p = ws + off; off += (bytes + 255) & ~(size_t)255; return p;
  };
  _Float16* xl  = (_Float16*)alloc((size_t)n*ODIM*2);  // 25.6 MB fp16
  _Float16* xr  = (_Float16*)alloc((size_t)n*ODIM*2);  // 25.6 MB fp16
  float* h      = (float*)alloc((size_t)n*CDIM*4);     // 6.4 MB layer-1 output
  int*   counts = (int*)alloc((size_t)n*4);
  int*   indptr = (int*)alloc((size_t)(n+1)*4);
  int*   rank   = (int*)alloc((size_t)e*4);
  int*   csr    = (int*)alloc((size_t)e*4);
  int*   bsums  = (int*)alloc((size_t)1024*4);

  int nblk = (n + 255) / 256;   // 196
  int ntiles = (n + 63) / 64;   // 782
  hipMemsetAsync(counts, 0, (size_t)n*4, stream);

  // layer-1 GEMM with fused CSR count (y==0, x<96 slice — dispatches first,
  // runs concurrently with the GEMM blocks that backfill)
  gemm_kernel<64,true><<<dim3(ntiles,5), 256, 0, stream>>>(
      x, W1l, b1l, W1r, b1r, xl, xr, n, src, dst, counts, rank, e);
  block_sum_kernel<<<nblk, 256, 0, stream>>>(counts, bsums, n);
  scan_bsums_kernel<<<1, 1024, 0, stream>>>(bsums, nblk);
  local_scan_kernel<<<nblk, 256, 0, stream>>>(counts, bsums, indptr, n);
  scatter_kernel<<<(e+255)/256, 256, 0, stream>>>(src, dst, rank, indptr, csr, e);

  edge_kernel<<<(n+3)/4, 256, 0, stream>>>(xl, xr, att1, bias1, indptr, csr, h, n, 1);
  // layer 2
  gemm_kernel<32,false><<<dim3(ntiles,4), 256, 0, stream>>>(
      h, W2l, b2l, W2r, b2r, xl, xr, n, nullptr, nullptr, nullptr, nullptr, 0);
  edge_kernel<<<(n+3)/4, 256, 0, stream>>>(xl, xr, att2, bias2, indptr, csr, (float*)d_out, n, 0);
}

// Round 12
// 330.903 us; speedup vs baseline: 1.2726x; 1.0006x over previous
//
#include <hip/hip_runtime.h>
#include <math.h>

// GATv2 2-layer: N=50000, E=800000, HEADS=8, C=32, ODIM=256, IN_C=64
#define HEADS 8
#define CDIM 32
#define ODIM 256

typedef _Float16 h2 __attribute__((ext_vector_type(2)));
typedef _Float16 h4 __attribute__((ext_vector_type(4)));
union H4 { h4 v; h2 p[2]; };

#if __has_builtin(__builtin_amdgcn_fdot2)
#define FDOT2(a,b,c) __builtin_amdgcn_fdot2((a),(b),(c),false)
#else
static __device__ __forceinline__ float fdot2_sw(h2 a, h2 b, float c){
  return fmaf((float)a.x, (float)b.x, fmaf((float)a.y, (float)b.y, c));
}
#define FDOT2(a,b,c) fdot2_sw((a),(b),(c))
#endif

__device__ __forceinline__ float lrelu(float v, float s){ return fmaxf(v, s*v); }

// ---- 3-phase parallel scan ----
__global__ void block_sum_kernel(const int* __restrict__ counts, int* __restrict__ bsums, int n){
  int i = blockIdx.x*256 + threadIdx.x;
  int v = (i < n) ? counts[i] : 0;
#pragma unroll
  for (int off=1; off<64; off<<=1) v += __shfl_xor(v, off);
  __shared__ int ws[4];
  int lane = threadIdx.x & 63, w = threadIdx.x >> 6;
  if (lane == 0) ws[w] = v;
  __syncthreads();
  if (threadIdx.x == 0) bsums[blockIdx.x] = ws[0]+ws[1]+ws[2]+ws[3];
}

__global__ __launch_bounds__(1024) void scan_bsums_kernel(int* __restrict__ bsums, int nb){
  __shared__ int s[1024];
  int t = threadIdx.x;
  int v = (t < nb) ? bsums[t] : 0;
  s[t] = v;
  __syncthreads();
  for (int off=1; off<1024; off<<=1){
    int u = (t >= off) ? s[t-off] : 0;
    __syncthreads();
    s[t] += u;
    __syncthreads();
  }
  if (t < nb) bsums[t] = s[t] - v;   // exclusive
}

__global__ void local_scan_kernel(const int* __restrict__ counts, const int* __restrict__ bsums,
                                  int* __restrict__ indptr, int n){
  __shared__ int s[256];
  int t = threadIdx.x;
  int i = blockIdx.x*256 + t;
  int v = (i < n) ? counts[i] : 0;
  s[t] = v;
  __syncthreads();
  for (int off=1; off<256; off<<=1){
    int u = (t >= off) ? s[t-off] : 0;
    __syncthreads();
    s[t] += u;
    __syncthreads();
  }
  int excl = s[t] - v + bsums[blockIdx.x];
  if (i < n) indptr[i] = excl;
  if (i == n-1) indptr[n] = excl + v;
}

// atomic-free scatter: csr[indptr[d] + rank] = s. Ranks per dst are a
// permutation of 0..cnt-1 -> csr[beg,end) fully written (poison-proof).
__global__ void scatter_kernel(const int* __restrict__ src, const int* __restrict__ dst,
                               const int* __restrict__ rank, const int* __restrict__ indptr,
                               int* __restrict__ csr_src, int e){
  int i = blockIdx.x*256 + threadIdx.x;
  if (i < e){
    int r = rank[i];
    if (r >= 0){
      int d = dst[i];
      csr_src[indptr[d] + r] = src[i];
    }
  }
}

// ---------------- dense GEMM: out[n,o] = sum_k X[n,k]*W[o,k] + b[o] ----------------
// LDS-tiled, l+r fused. Block = 128 nodes x 64 outputs, micro-tile 8x4x{l,r}
// (64 accumulators): 16 ds_read_b128 per 256 scalar FMAs per 4-k chunk —
// 2x the FMA/LDS-byte ratio of the old 4x4 tile (R10 showed VALUBusy 40%,
// LDS-wait-bound). VGPR ~150 -> 2 waves/SIMD; LDS 70KB (K=64) -> 2 blocks/CU.
// Both outputs fp16. FUSE_COUNT: y==0, x<96 blocks run CSR count+rank
// concurrently (dispatch first, other y==0 blocks no-op and backfill).
template<int K, bool FUSE_COUNT>
__global__ __launch_bounds__(256, 2) void gemm_kernel(const float* __restrict__ X,
    const float* __restrict__ Wl, const float* __restrict__ bl,
    const float* __restrict__ Wr, const float* __restrict__ br,
    _Float16* __restrict__ outl, _Float16* __restrict__ outr, int n,
    const int* __restrict__ src, const int* __restrict__ dst,
    int* __restrict__ counts, int* __restrict__ rank, int e){
  if (FUSE_COUNT && blockIdx.y == 0){
    const int CB = 96;
    if (blockIdx.x < CB){
      int stride = CB*256;
      for (int i = blockIdx.x*256 + threadIdx.x; i < e; i += stride){
        int s = src[i], d = dst[i];
        int r = -1;
        if (s != d) r = atomicAdd(counts + d, 1);   // src==dst masked (PyG removes)
        rank[i] = r;
      }
    }
    return;
  }
  const int KP = K + 4;
  __shared__ float xt[128*(K+4)];
  __shared__ float wt[2][64*(K+4)];
  int t = threadIdx.x;
  int n0 = blockIdx.x*128;
  int o0 = (FUSE_COUNT ? (blockIdx.y-1) : blockIdx.y)*64;

  for (int idx = t; idx < 128*(K/4); idx += 256){
    int row = idx/(K/4), c = (idx%(K/4))*4;
    int node = n0 + row; if (node >= n) node = n-1;   // clamp; stores guarded
    *(float4*)(xt + row*KP + c) = *(const float4*)(X + (size_t)node*K + c);
  }
  for (int idx = t; idx < 64*(K/4); idx += 256){
    int row = idx/(K/4), c = (idx%(K/4))*4;
    *(float4*)(wt[0] + row*KP + c) = *(const float4*)(Wl + (size_t)(o0+row)*K + c);
    *(float4*)(wt[1] + row*KP + c) = *(const float4*)(Wr + (size_t)(o0+row)*K + c);
  }
  __syncthreads();

  int og = t & 15;          // outputs o0 + og + 16j  (j<4)
  int ng = t >> 4;          // nodes   n0 + ng + 16i  (i<8)
  float accl[8][4] = {{0.f}}, accr[8][4] = {{0.f}};

#pragma unroll 2
  for (int kk = 0; kk < K; kk += 4){
    float4 xv[8], wl4[4], wr4[4];
#pragma unroll
    for (int i=0;i<8;i++) xv[i] = *(const float4*)(xt + (ng+16*i)*KP + kk);
#pragma unroll
    for (int j=0;j<4;j++){
      wl4[j] = *(const float4*)(wt[0] + (og+16*j)*KP + kk);
      wr4[j] = *(const float4*)(wt[1] + (og+16*j)*KP + kk);
    }
#pragma unroll
    for (int i=0;i<8;i++){
#pragma unroll
      for (int j=0;j<4;j++){
        accl[i][j] = fmaf(xv[i].x, wl4[j].x, fmaf(xv[i].y, wl4[j].y,
                     fmaf(xv[i].z, wl4[j].z, fmaf(xv[i].w, wl4[j].w, accl[i][j]))));
        accr[i][j] = fmaf(xv[i].x, wr4[j].x, fmaf(xv[i].y, wr4[j].y,
                     fmaf(xv[i].z, wr4[j].z, fmaf(xv[i].w, wr4[j].w, accr[i][j]))));
      }
    }
  }

  float bvl[4], bvr[4];
#pragma unroll
  for (int j=0;j<4;j++){ bvl[j] = bl[o0+og+16*j]; bvr[j] = br[o0+og+16*j]; }
#pragma unroll
  for (int i=0;i<8;i++){
    int node = n0 + ng + 16*i;
    if (node < n){
      _Float16* pl = outl + (size_t)node*ODIM + o0 + og;
      _Float16* pr = outr + (size_t)node*ODIM + o0 + og;
#pragma unroll
      for (int j=0;j<4;j++){
        pl[16*j] = (_Float16)(accl[i][j] + bvl[j]);
        pr[16*j] = (_Float16)(accr[i][j] + bvr[j]);
      }
    }
  }
}

// ---------------- fused edge softmax + aggregate, one wave per node ----------------
// R6-proven memory structure (1 edge/iter, depth-2 guarded prefetch, h4/lane
// coalesced 512B/wave) + packed-fp16 score path (R10/R11-proven).
__global__ __launch_bounds__(256) void edge_kernel(
    const _Float16* __restrict__ xl, const _Float16* __restrict__ xr,
    const float* __restrict__ att, const float* __restrict__ bias,
    const int* __restrict__ indptr, const int* __restrict__ csr_src,
    float* __restrict__ out, int n, int act)
{
  int wid = blockIdx.x*4 + (threadIdx.x >> 6);
  if (wid >= n) return;
  int lane = threadIdx.x & 63;
  const float LOG2E = 1.44269504088896341f;

  float4 attf = *(const float4*)(att + 4*lane);
  h2 at0 = (h2){(_Float16)(attf.x*LOG2E), (_Float16)(attf.y*LOG2E)};
  h2 at1 = (h2){(_Float16)(attf.z*LOG2E), (_Float16)(attf.w*LOG2E)};
  const h2 c02 = {(_Float16)0.2f, (_Float16)0.2f};

  H4 xrh; xrh.v = *(const h4*)(xr + (size_t)wid*ODIM + 4*lane);
  H4 self; self.v = *(const h4*)(xl + (size_t)wid*ODIM + 4*lane);

  auto score = [&](const H4& c)->float{
    h2 t0 = c.p[0] + xrh.p[0];
    h2 t1 = c.p[1] + xrh.p[1];
    h2 q0 = __builtin_elementwise_max(t0, t0 * c02);
    h2 q1 = __builtin_elementwise_max(t1, t1 * c02);
    float d = FDOT2(q0, at0, FDOT2(q1, at1, 0.f));
    d += __shfl_xor(d, 1);   // reduce over the 8 lanes of this head
    d += __shfl_xor(d, 2);
    d += __shfl_xor(d, 4);
    return d;
  };

  // self-loop seeds the accumulator
  float w0 = exp2f(score(self));
  float denom = w0;
  float4 acc;
  acc.x = w0 * (float)self.v.x;
  acc.y = w0 * (float)self.v.y;
  acc.z = w0 * (float)self.v.z;
  acc.w = w0 * (float)self.v.w;

  int beg = __builtin_amdgcn_readfirstlane(indptr[wid]);
  int end = __builtin_amdgcn_readfirstlane(indptr[wid+1]);
  int cnt = end - beg;
  H4 r0, r1;
  r0.v = (h4){}; r1.v = (h4){};
  if (cnt > 0){
    int s0 = __builtin_amdgcn_readfirstlane(csr_src[beg]);
    r0.v = *(const h4*)(xl + (size_t)s0*ODIM + 4*lane);
  }
  if (cnt > 1){
    int s1 = __builtin_amdgcn_readfirstlane(csr_src[beg+1]);
    r1.v = *(const h4*)(xl + (size_t)s1*ODIM + 4*lane);
  }
  for (int k = 0; k < cnt; ++k){
    H4 cur = r0; r0 = r1;
    if (k+2 < cnt){
      int s2 = __builtin_amdgcn_readfirstlane(csr_src[beg+k+2]);
      r1.v = *(const h4*)(xl + (size_t)s2*ODIM + 4*lane);   // prefetch 2 ahead
    }
    float pe = exp2f(score(cur));
    denom += pe;
    acc.x = fmaf(pe, (float)cur.v.x, acc.x);   // v_fma_mix (single-use cvt)
    acc.y = fmaf(pe, (float)cur.v.y, acc.y);
    acc.z = fmaf(pe, (float)cur.v.z, acc.z);
    acc.w = fmaf(pe, (float)cur.v.w, acc.w);
  }
  float inv = 1.f/denom;
  float vx = acc.x*inv, vy = acc.y*inv, vz = acc.z*inv, vw = acc.w*inv;
  // mean over heads: sum lanes {l, l^8, l^16, l^32}
  vx += __shfl_xor(vx, 8);  vx += __shfl_xor(vx, 16);  vx += __shfl_xor(vx, 32);
  vy += __shfl_xor(vy, 8);  vy += __shfl_xor(vy, 16);  vy += __shfl_xor(vy, 32);
  vz += __shfl_xor(vz, 8);  vz += __shfl_xor(vz, 16);  vz += __shfl_xor(vz, 32);
  vw += __shfl_xor(vw, 8);  vw += __shfl_xor(vw, 16);  vw += __shfl_xor(vw, 32);
  if (lane < 8){
    float4 bv = *(const float4*)(bias + 4*lane);
    float ox = vx*0.125f + bv.x;
    float oy = vy*0.125f + bv.y;
    float oz = vz*0.125f + bv.z;
    float ow = vw*0.125f + bv.w;
    if (act){
      ox = lrelu(ox, 0.01f); oy = lrelu(oy, 0.01f);
      oz = lrelu(oz, 0.01f); ow = lrelu(ow, 0.01f);
    }
    *(float4*)(out + (size_t)wid*CDIM + 4*lane) = make_float4(ox, oy, oz, ow);
  }
}

extern "C" void kernel_launch(void* const* d_in, const int* in_sizes, int n_in,
                              void* d_out, int out_size, void* d_ws, size_t ws_size,
                              hipStream_t stream){
  (void)n_in; (void)out_size; (void)ws_size;
  const float* x    = (const float*)d_in[0];
  const int*   ei   = (const int*)d_in[1];
  const float* W1l  = (const float*)d_in[2];
  const float* b1l  = (const float*)d_in[3];
  const float* W1r  = (const float*)d_in[4];
  const float* b1r  = (const float*)d_in[5];
  const float* att1 = (const float*)d_in[6];
  const float* bias1= (const float*)d_in[7];
  const float* W2l  = (const float*)d_in[8];
  const float* b2l  = (const float*)d_in[9];
  const float* W2r  = (const float*)d_in[10];
  const float* b2r  = (const float*)d_in[11];
  const float* att2 = (const float*)d_in[12];
  const float* bias2= (const float*)d_in[13];
  int n = in_sizes[0] / 64;   // 50000
  int e = in_sizes[1] / 2;    // 800000
  const int* src = ei;
  const int* dst = ei + e;

  char* ws = (char*)d_ws;
  size_t off = 0;
  auto alloc = [&](size_t bytes)->char*{
    char* p = ws + off; off += (bytes + 255) & ~(size_t)255; return p;
  };
  _Float16* xl  = (_Float16*)alloc((size_t)n*ODIM*2);  // 25.6 MB fp16
  _Float16* xr  = (_Float16*)alloc((size_t)n*ODIM*2);  // 25.6 MB fp16
  float* h      = (float*)alloc((size_t)n*CDIM*4);     // 6.4 MB layer-1 output
  int*   counts = (int*)alloc((size_t)n*4);
  int*   indptr = (int*)alloc((size_t)(n+1)*4);
  int*   rank   = (int*)alloc((size_t)e*4);
  int*   csr    = (int*)alloc((size_t)e*4);
  int*   bsums  = (int*)alloc((size_t)1024*4);

  int nblk = (n + 255) / 256;    // 196
  int ntiles = (n + 127) / 128;  // 391
  hipMemsetAsync(counts, 0, (size_t)n*4, stream);

  // layer-1 GEMM with fused CSR count (y==0, x<96 slice — dispatches first,
  // runs concurrently with the GEMM blocks that backfill)
  gemm_kernel<64,true><<<dim3(ntiles,5), 256, 0, stream>>>(
      x, W1l, b1l, W1r, b1r, xl, xr, n, src, dst, counts, rank, e);
  block_sum_kernel<<<nblk, 256, 0, stream>>>(counts, bsums, n);
  scan_bsums_kernel<<<1, 1024, 0, stream>>>(bsums, nblk);
  local_scan_kernel<<<nblk, 256, 0, stream>>>(counts, bsums, indptr, n);
  scatter_kernel<<<(e+255)/256, 256, 0, stream>>>(src, dst, rank, indptr, csr, e);

  edge_kernel<<<(n+3)/4, 256, 0, stream>>>(xl, xr, att1, bias1, indptr, csr, h, n, 1);
  // layer 2
  gemm_kernel<32,false><<<dim3(ntiles,4), 256, 0, stream>>>(
      h, W2l, b2l, W2r, b2r, xl, xr, n, nullptr, nullptr, nullptr, nullptr, 0);
  edge_kernel<<<(n+3)/4, 256, 0, stream>>>(xl, xr, att2, bias2, indptr, csr, (float*)d_out, n, 0);
}